// Round 1
// baseline (35.291 us; speedup 1.0000x reference)
//
#include <hip/hip_runtime.h>

#define FAPE_EPS   1e-4f
#define FAPE_CLAMP 10.0f
#define FAPE_Z     10.0f

// One block per (batch, frame). Each block:
//  - loads frame data (R_pred, t_pred, R_true, t_true) into LDS -> registers
//  - strides over all A atoms of its batch, computing
//      x = R^T (p - t) for pred and true, dist = sqrt(|dx|^2 + eps),
//      clamped at 10, weighted by mask
//  - block-reduces and atomicAdds into acc[batch]
__global__ void fape_frames_kernel(const float* __restrict__ Rp,
                                   const float* __restrict__ tp,
                                   const float* __restrict__ pp,
                                   const float* __restrict__ mask,
                                   const float* __restrict__ Rt,
                                   const float* __restrict__ tt,
                                   const float* __restrict__ pt,
                                   float* __restrict__ acc,
                                   int N, int A) {
    const int bi    = blockIdx.x;      // 0 .. b*N-1
    const int batch = bi / N;
    const int tid   = threadIdx.x;

    __shared__ float sF[24];           // [0:9) Rp, [9:12) tp, [12:21) Rt, [21:24) tt
    if (tid < 9) { sF[tid]      = Rp[bi * 9 + tid];
                   sF[12 + tid] = Rt[bi * 9 + tid]; }
    if (tid < 3) { sF[9 + tid]  = tp[bi * 3 + tid];
                   sF[21 + tid] = tt[bi * 3 + tid]; }
    __syncthreads();

    // registers (broadcast reads, no bank conflicts)
    const float rp00 = sF[0], rp01 = sF[1], rp02 = sF[2];
    const float rp10 = sF[3], rp11 = sF[4], rp12 = sF[5];
    const float rp20 = sF[6], rp21 = sF[7], rp22 = sF[8];
    const float tp0  = sF[9], tp1  = sF[10], tp2 = sF[11];
    const float rt00 = sF[12], rt01 = sF[13], rt02 = sF[14];
    const float rt10 = sF[15], rt11 = sF[16], rt12 = sF[17];
    const float rt20 = sF[18], rt21 = sF[19], rt22 = sF[20];
    const float tt0  = sF[21], tt1  = sF[22], tt2 = sF[23];

    const float* __restrict__ ppb = pp   + (size_t)batch * A * 3;
    const float* __restrict__ ptb = pt   + (size_t)batch * A * 3;
    const float* __restrict__ mb  = mask + (size_t)batch * A;

    float local = 0.0f;
    for (int j = tid; j < A; j += blockDim.x) {
        const float p0 = ppb[j * 3 + 0], p1 = ppb[j * 3 + 1], p2 = ppb[j * 3 + 2];
        const float q0 = ptb[j * 3 + 0], q1 = ptb[j * 3 + 1], q2 = ptb[j * 3 + 2];

        const float a0 = p0 - tp0, a1 = p1 - tp1, a2 = p2 - tp2;
        const float b0 = q0 - tt0, b1 = q1 - tt1, b2 = q2 - tt2;

        // x[o] = sum_p R[p][o] * a[p]  (R^T a)
        const float xp0 = rp00 * a0 + rp10 * a1 + rp20 * a2;
        const float xp1 = rp01 * a0 + rp11 * a1 + rp21 * a2;
        const float xp2 = rp02 * a0 + rp12 * a1 + rp22 * a2;
        const float xt0 = rt00 * b0 + rt10 * b1 + rt20 * b2;
        const float xt1 = rt01 * b0 + rt11 * b1 + rt21 * b2;
        const float xt2 = rt02 * b0 + rt12 * b1 + rt22 * b2;

        const float d0 = xp0 - xt0, d1 = xp1 - xt1, d2 = xp2 - xt2;
        const float dist = sqrtf(d0 * d0 + d1 * d1 + d2 * d2 + FAPE_EPS);
        local += fminf(dist, FAPE_CLAMP) * mb[j];
    }

    // wave64 shuffle reduce
    for (int off = 32; off > 0; off >>= 1)
        local += __shfl_down(local, off);

    __shared__ float swave[4];         // 256 threads = 4 waves
    if ((tid & 63) == 0) swave[tid >> 6] = local;
    __syncthreads();
    if (tid == 0) {
        const float s = swave[0] + swave[1] + swave[2] + swave[3];
        atomicAdd(&acc[batch], s);
    }
}

// One block per batch: n_atoms = max(sum(mask), 1); out = acc / (n_atoms * N * Z)
__global__ void fape_finalize_kernel(const float* __restrict__ mask,
                                     const float* __restrict__ acc,
                                     float* __restrict__ out,
                                     int N, int A) {
    const int batch = blockIdx.x;
    const int tid   = threadIdx.x;
    const float* __restrict__ mb = mask + (size_t)batch * A;

    float local = 0.0f;
    for (int j = tid; j < A; j += blockDim.x) local += mb[j];
    for (int off = 32; off > 0; off >>= 1) local += __shfl_down(local, off);

    __shared__ float swave[4];
    if ((tid & 63) == 0) swave[tid >> 6] = local;
    __syncthreads();
    if (tid == 0) {
        const float n = fmaxf(swave[0] + swave[1] + swave[2] + swave[3], 1.0f);
        out[batch] = acc[batch] / (n * (float)N * FAPE_Z);
    }
}

extern "C" void kernel_launch(void* const* d_in, const int* in_sizes, int n_in,
                              void* d_out, int out_size, void* d_ws, size_t ws_size,
                              hipStream_t stream) {
    const float* Rp   = (const float*)d_in[0];  // [b,N,3,3]
    const float* tp   = (const float*)d_in[1];  // [b,N,3]
    const float* pp   = (const float*)d_in[2];  // [b,N,14,3]
    const float* mask = (const float*)d_in[3];  // [b,N,14]
    const float* Rt   = (const float*)d_in[4];
    const float* tt   = (const float*)d_in[5];
    const float* pt   = (const float*)d_in[6];
    float* out = (float*)d_out;

    const int b  = out_size;              // output is [b]
    const int bN = in_sizes[1] / 3;       // translations: b*N*3
    const int N  = bN / b;
    const int A  = N * 14;

    float* acc = (float*)d_ws;
    hipMemsetAsync(acc, 0, b * sizeof(float), stream);

    fape_frames_kernel<<<dim3(bN), dim3(256), 0, stream>>>(
        Rp, tp, pp, mask, Rt, tt, pt, acc, N, A);
    fape_finalize_kernel<<<dim3(b), dim3(256), 0, stream>>>(
        mask, acc, out, N, A);
}

// Round 2
// 29.681 us; speedup vs baseline: 1.1890x; 1.1890x over previous
//
#include <hip/hip_runtime.h>

#define FAPE_EPS   1e-4f
#define FAPE_CLAMP 10.0f
#define FAPE_Z     10.0f

constexpr int TPB   = 256;        // threads per block
constexpr int FPB   = 8;          // frames per block
constexpr int APT   = 4;          // atoms per thread
constexpr int ATILE = TPB * APT;  // 1024 atoms per block tile

// Tiled cross product: each block owns FPB frames x ATILE atoms.
// Atoms (pred, true, mask) are loaded ONCE per thread as float4 vectors and
// reused across all FPB frames; frame data is read via block-uniform indices
// (scalar-load / L1-broadcast path). Per pair:
//   x = c + Rp^T p - Rt^T q,  c = Rt^T t_t - Rp^T t_p   (18 FMA + 3 FMA + sqrt)
__global__ __launch_bounds__(TPB) void fape_frames_kernel(
        const float* __restrict__ Rp, const float* __restrict__ tp,
        const float* __restrict__ pp, const float* __restrict__ mask,
        const float* __restrict__ Rt, const float* __restrict__ tt,
        const float* __restrict__ pt, float* __restrict__ acc,
        int N, int A, int fTilesPerBatch, int atomTiles) {

    const int tid   = threadIdx.x;
    int t           = blockIdx.x;
    const int atile = t % atomTiles;
    const int ft    = t / atomTiles;
    const int batch = ft / fTilesPerBatch;
    const int f0    = (ft % fTilesPerBatch) * FPB;   // frame base within batch

    const float* __restrict__ ppb = pp   + (size_t)batch * A * 3;
    const float* __restrict__ ptb = pt   + (size_t)batch * A * 3;
    const float* __restrict__ mb  = mask + (size_t)batch * A;

    // ---- load 4 atoms into registers (7 x float4) ----
    float p[APT][3], q[APT][3], m[APT];
    const int j0 = atile * ATILE + tid * APT;
    if (j0 + APT <= A) {
        const float4* p4 = reinterpret_cast<const float4*>(ppb + (size_t)j0 * 3);
        const float4* q4 = reinterpret_cast<const float4*>(ptb + (size_t)j0 * 3);
        const float4  P0 = p4[0], P1 = p4[1], P2 = p4[2];
        const float4  Q0 = q4[0], Q1 = q4[1], Q2 = q4[2];
        const float4  M  = *reinterpret_cast<const float4*>(mb + j0);
        p[0][0]=P0.x; p[0][1]=P0.y; p[0][2]=P0.z;
        p[1][0]=P0.w; p[1][1]=P1.x; p[1][2]=P1.y;
        p[2][0]=P1.z; p[2][1]=P1.w; p[2][2]=P2.x;
        p[3][0]=P2.y; p[3][1]=P2.z; p[3][2]=P2.w;
        q[0][0]=Q0.x; q[0][1]=Q0.y; q[0][2]=Q0.z;
        q[1][0]=Q0.w; q[1][1]=Q1.x; q[1][2]=Q1.y;
        q[2][0]=Q1.z; q[2][1]=Q1.w; q[2][2]=Q2.x;
        q[3][0]=Q2.y; q[3][1]=Q2.z; q[3][2]=Q2.w;
        m[0]=M.x; m[1]=M.y; m[2]=M.z; m[3]=M.w;
    } else {
#pragma unroll
        for (int k = 0; k < APT; ++k) {
            const int j = j0 + k;
            if (j < A) {
                p[k][0]=ppb[j*3+0]; p[k][1]=ppb[j*3+1]; p[k][2]=ppb[j*3+2];
                q[k][0]=ptb[j*3+0]; q[k][1]=ptb[j*3+1]; q[k][2]=ptb[j*3+2];
                m[k]=mb[j];
            } else {
                p[k][0]=p[k][1]=p[k][2]=0.f;
                q[k][0]=q[k][1]=q[k][2]=0.f;
                m[k]=0.f;
            }
        }
    }

    float local = 0.0f;
    for (int f = 0; f < FPB; ++f) {
        const int fl = f0 + f;
        if (fl >= N) break;
        const size_t fi = (size_t)batch * N + fl;   // block-uniform
        const float* __restrict__ rp = Rp + fi * 9;
        const float* __restrict__ rt = Rt + fi * 9;
        const float* __restrict__ tv = tp + fi * 3;
        const float* __restrict__ uv = tt + fi * 3;

        const float rp00=rp[0], rp01=rp[1], rp02=rp[2];
        const float rp10=rp[3], rp11=rp[4], rp12=rp[5];
        const float rp20=rp[6], rp21=rp[7], rp22=rp[8];
        const float rt00=rt[0], rt01=rt[1], rt02=rt[2];
        const float rt10=rt[3], rt11=rt[4], rt12=rt[5];
        const float rt20=rt[6], rt21=rt[7], rt22=rt[8];
        const float tp0=tv[0], tp1=tv[1], tp2=tv[2];
        const float tt0=uv[0], tt1=uv[1], tt2=uv[2];

        // c = Rt^T t_t - Rp^T t_p
        const float c0 = rt00*tt0 + rt10*tt1 + rt20*tt2 - (rp00*tp0 + rp10*tp1 + rp20*tp2);
        const float c1 = rt01*tt0 + rt11*tt1 + rt21*tt2 - (rp01*tp0 + rp11*tp1 + rp21*tp2);
        const float c2 = rt02*tt0 + rt12*tt1 + rt22*tt2 - (rp02*tp0 + rp12*tp1 + rp22*tp2);

#pragma unroll
        for (int k = 0; k < APT; ++k) {
            float x0 = c0 + rp00*p[k][0] + rp10*p[k][1] + rp20*p[k][2]
                          - rt00*q[k][0] - rt10*q[k][1] - rt20*q[k][2];
            float x1 = c1 + rp01*p[k][0] + rp11*p[k][1] + rp21*p[k][2]
                          - rt01*q[k][0] - rt11*q[k][1] - rt21*q[k][2];
            float x2 = c2 + rp02*p[k][0] + rp12*p[k][1] + rp22*p[k][2]
                          - rt02*q[k][0] - rt12*q[k][1] - rt22*q[k][2];
            const float d = sqrtf(x0*x0 + x1*x1 + x2*x2 + FAPE_EPS);
            local += fminf(d, FAPE_CLAMP) * m[k];
        }
    }

    // wave64 shuffle reduce + cross-wave LDS reduce
    for (int off = 32; off > 0; off >>= 1)
        local += __shfl_down(local, off);

    __shared__ float swave[TPB / 64];
    if ((tid & 63) == 0) swave[tid >> 6] = local;
    __syncthreads();
    if (tid == 0) {
        float s = 0.f;
#pragma unroll
        for (int w = 0; w < TPB / 64; ++w) s += swave[w];
        atomicAdd(&acc[batch], s);
    }
}

// One block per batch: n_atoms = max(sum(mask), 1); out = acc / (n_atoms * N * Z)
__global__ __launch_bounds__(TPB) void fape_finalize_kernel(
        const float* __restrict__ mask, const float* __restrict__ acc,
        float* __restrict__ out, int N, int A) {
    const int batch = blockIdx.x;
    const int tid   = threadIdx.x;
    const float* __restrict__ mb = mask + (size_t)batch * A;

    float local = 0.0f;
    for (int j = tid * 4; j + 4 <= A; j += TPB * 4) {
        const float4 M = *reinterpret_cast<const float4*>(mb + j);
        local += M.x + M.y + M.z + M.w;
    }
    // tail (A not multiple of 4*TPB)
    for (int j = (A & ~3) + tid; j < A; j += TPB) local += mb[j];

    for (int off = 32; off > 0; off >>= 1) local += __shfl_down(local, off);

    __shared__ float swave[TPB / 64];
    if ((tid & 63) == 0) swave[tid >> 6] = local;
    __syncthreads();
    if (tid == 0) {
        float s = 0.f;
#pragma unroll
        for (int w = 0; w < TPB / 64; ++w) s += swave[w];
        const float n = fmaxf(s, 1.0f);
        out[batch] = acc[batch] / (n * (float)N * FAPE_Z);
    }
}

extern "C" void kernel_launch(void* const* d_in, const int* in_sizes, int n_in,
                              void* d_out, int out_size, void* d_ws, size_t ws_size,
                              hipStream_t stream) {
    const float* Rp   = (const float*)d_in[0];  // [b,N,3,3]
    const float* tp   = (const float*)d_in[1];  // [b,N,3]
    const float* pp   = (const float*)d_in[2];  // [b,N,14,3]
    const float* mask = (const float*)d_in[3];  // [b,N,14]
    const float* Rt   = (const float*)d_in[4];
    const float* tt   = (const float*)d_in[5];
    const float* pt   = (const float*)d_in[6];
    float* out = (float*)d_out;

    const int b  = out_size;
    const int bN = in_sizes[1] / 3;
    const int N  = bN / b;
    const int A  = N * 14;

    const int fTilesPerBatch = (N + FPB - 1) / FPB;
    const int atomTiles      = (A + ATILE - 1) / ATILE;
    const int nBlocks        = b * fTilesPerBatch * atomTiles;

    float* acc = (float*)d_ws;
    hipMemsetAsync(acc, 0, b * sizeof(float), stream);

    fape_frames_kernel<<<dim3(nBlocks), dim3(TPB), 0, stream>>>(
        Rp, tp, pp, mask, Rt, tt, pt, acc, N, A, fTilesPerBatch, atomTiles);
    fape_finalize_kernel<<<dim3(b), dim3(TPB), 0, stream>>>(
        mask, acc, out, N, A);
}